// Round 2
// baseline (56878.052 us; speedup 1.0000x reference)
//
#include <hip/hip_runtime.h>
#include <hip/hip_fp16.h>

#define BB   64
#define TDEC 400
#define TENC 512
#define DD   256
#define PRE  128
#define NOUT 400
#define G3   768
#define NBLK 256
#define NTHR 256

// ---------------- fast math ----------------
__device__ __forceinline__ float fsig(float x) {
    return __builtin_amdgcn_rcpf(1.0f + __expf(-x));
}
__device__ __forceinline__ float ftanh(float x) {
    // 1 - 2/(e^{2x}+1); handles +-inf correctly (-> +-1), no clamp needed
    float t = __expf(2.0f * x);
    return 1.0f - 2.0f * __builtin_amdgcn_rcpf(t + 1.0f);
}
// 8-term fp16xfp16 -> fp32 dot from two 16B packets
__device__ __forceinline__ float dot8f(float4 w, float4 x, float acc) {
    union { float4 f; __half2 h[4]; } uw, ux;
    uw.f = w; ux.f = x;
    #pragma unroll
    for (int k = 0; k < 4; k++) {
        float2 a = __half22float2(uw.h[k]);
        float2 b = __half22float2(ux.h[k]);
        acc = fmaf(a.x, b.x, acc);
        acc = fmaf(a.y, b.y, acc);
    }
    return acc;
}

// ---------------- device-scope grid barrier (sense-reversal) ----------------
__device__ __forceinline__ void gbar(int* cnt, int* gen) {
    __syncthreads();
    if (threadIdx.x == 0) {
        int g = __hip_atomic_load(gen, __ATOMIC_RELAXED, __HIP_MEMORY_SCOPE_AGENT);
        int a = __hip_atomic_fetch_add(cnt, 1, __ATOMIC_ACQ_REL, __HIP_MEMORY_SCOPE_AGENT);
        if (a == NBLK - 1) {
            __hip_atomic_store(cnt, 0, __ATOMIC_RELAXED, __HIP_MEMORY_SCOPE_AGENT);
            __hip_atomic_store(gen, g + 1, __ATOMIC_RELEASE, __HIP_MEMORY_SCOPE_AGENT);
        } else {
            while (__hip_atomic_load(gen, __ATOMIC_ACQUIRE, __HIP_MEMORY_SCOPE_AGENT) == g) {
                __builtin_amdgcn_s_sleep(2);
            }
        }
    }
    __syncthreads();
}

// ---------------- prenet: p_h = fp16(relu(relu(x@W1+b1)@W2+b2)) ----------------
__global__ __launch_bounds__(256) void prenet_kernel(
    const float* __restrict__ x, const float* __restrict__ W1, const float* __restrict__ b1,
    const float* __restrict__ W2, const float* __restrict__ b2, __half* __restrict__ p_h)
{
    __shared__ __align__(16) float xs[8][NOUT];
    __shared__ __align__(16) float hs[8][DD];
    const int row0 = blockIdx.x * 8;
    const int tid = threadIdx.x;
    for (int idx = tid; idx < 8 * NOUT; idx += 256) {
        int m = idx / NOUT, i = idx - m * NOUT;
        xs[m][i] = x[(size_t)(row0 + m) * NOUT + i];
    }
    __syncthreads();
    {
        const int j = tid;
        float acc[8];
        float bj = b1[j];
        #pragma unroll
        for (int m = 0; m < 8; m++) acc[m] = bj;
        #pragma unroll 4
        for (int i = 0; i < NOUT; i++) {
            float w = W1[i * DD + j];
            #pragma unroll
            for (int m = 0; m < 8; m++) acc[m] = fmaf(xs[m][i], w, acc[m]);
        }
        #pragma unroll
        for (int m = 0; m < 8; m++) hs[m][j] = fmaxf(acc[m], 0.0f);
    }
    __syncthreads();
    if (tid < PRE) {
        const int j = tid;
        float acc[8];
        float bj = b2[j];
        #pragma unroll
        for (int m = 0; m < 8; m++) acc[m] = bj;
        #pragma unroll 4
        for (int i = 0; i < DD; i++) {
            float w = W2[i * PRE + j];
            #pragma unroll
            for (int m = 0; m < 8; m++) acc[m] = fmaf(hs[m][i], w, acc[m]);
        }
        #pragma unroll
        for (int m = 0; m < 8; m++)
            p_h[(size_t)(row0 + m) * PRE + j] = __float2half(fmaxf(acc[m], 0.0f));
    }
}

// ---------------- keys_h = fp16(memory @ Wm) ----------------
__global__ __launch_bounds__(256) void keys_kernel(
    const float* __restrict__ mem, const float* __restrict__ Wm, __half* __restrict__ keys_h)
{
    __shared__ __align__(16) float xs[8][DD];
    const int row0 = blockIdx.x * 8;
    const int tid = threadIdx.x;
    for (int idx = tid; idx < 8 * DD; idx += 256) {
        int m = idx >> 8, i = idx & 255;
        xs[m][i] = mem[(size_t)(row0 + m) * DD + i];
    }
    __syncthreads();
    const int j = tid;
    float acc[8] = {0.f,0.f,0.f,0.f,0.f,0.f,0.f,0.f};
    #pragma unroll 4
    for (int i = 0; i < DD; i++) {
        float w = Wm[i * DD + j];
        #pragma unroll
        for (int m = 0; m < 8; m++) acc[m] = fmaf(xs[m][i], w, acc[m]);
    }
    #pragma unroll
    for (int m = 0; m < 8; m++) keys_h[(size_t)(row0 + m) * DD + j] = __float2half(acc[m]);
}

// ---------------- fp32 -> fp16 convert (pairwise) ----------------
__global__ __launch_bounds__(256) void cvt_half_kernel(
    const float* __restrict__ src, __half* __restrict__ dst, int n2)
{
    int idx = blockIdx.x * 256 + threadIdx.x;
    if (idx < n2) {
        float2 v = ((const float2*)src)[idx];
        ((__half2*)dst)[idx] = __floats2half2_rn(v.x, v.y);
    }
}

// ---------------- transpose + convert: src[R][C] fp32 -> dst[C][R] fp16 ----------------
__global__ __launch_bounds__(256) void transpose_cvt_kernel(
    const float* __restrict__ src, __half* __restrict__ dst, int R, int C)
{
    int idx = blockIdx.x * 256 + threadIdx.x;
    if (idx < R * C) {
        int c = idx / R, r = idx - c * R;
        dst[idx] = __float2half(src[r * C + c]);
    }
}

// ---------------- y = ahist(fp16) @ Wo + bo ----------------
__global__ __launch_bounds__(448) void out_kernel(
    const __half* __restrict__ ah, const float* __restrict__ Wo, const float* __restrict__ bo,
    float* __restrict__ y)
{
    __shared__ __align__(16) float xs[8][DD];
    const int row0 = blockIdx.x * 8;
    const int tid = threadIdx.x;
    for (int idx = tid; idx < 8 * DD; idx += 448) {
        int m = idx >> 8, i = idx & 255;
        xs[m][i] = __half2float(ah[(size_t)(row0 + m) * DD + i]);
    }
    __syncthreads();
    if (tid < NOUT) {
        const int j = tid;
        float acc[8];
        float bj = bo[j];
        #pragma unroll
        for (int m = 0; m < 8; m++) acc[m] = bj;
        #pragma unroll 4
        for (int i = 0; i < DD; i++) {
            float w = Wo[i * NOUT + j];
            #pragma unroll
            for (int m = 0; m < 8; m++) acc[m] = fmaf(xs[m][i], w, acc[m]);
        }
        #pragma unroll
        for (int m = 0; m < 8; m++) y[(size_t)(row0 + m) * NOUT + j] = acc[m];
    }
}

// ---------------- persistent weight-stationary cooperative decoder ----------------
// 256 blocks x 256 threads. Roles per step:
//  A: GRU0   (g = blk&7 batch-group, ht = blk>>3 h-dim tile of 8) -> h0
//  B: GRU1   (same mapping)                                       -> h1
//  C: q, scores, exp, partial den/num (b = blk&63, eq = blk>>6 e-chunk of 128)
//  D: ctx + attn = [h1|ctx]@Wa        (b = blk&63, dq = blk>>6 out-col chunk of 64)
__global__ __launch_bounds__(NTHR) void decoder_kernel(
    const __half* __restrict__ p_h,   const __half* __restrict__ keys_h,
    const __half* __restrict__ mem_h,
    const __half* __restrict__ k0T,   const __half* __restrict__ r0T,
    const __half* __restrict__ k1T,   const __half* __restrict__ r1T,
    const __half* __restrict__ Wq_h,  const __half* __restrict__ Wa_h,
    const float* __restrict__ bi0, const float* __restrict__ br0,
    const float* __restrict__ bi1, const float* __restrict__ br1,
    const float* __restrict__ v,
    float* __restrict__ num_part, float* __restrict__ den_part,
    __half* __restrict__ att_h,
    float* __restrict__ h0_f, __half* __restrict__ h0_h,
    float* __restrict__ h1_f, __half* __restrict__ h1_h,
    __half* __restrict__ ahist_h,
    int* __restrict__ bar_cnt, int* __restrict__ bar_gen)
{
    // weight slices (fp16, LDS-resident all 400 steps); strides padded for banks
    __shared__ __align__(16) __half wA [24 * 392];   // k0T rows (384 in-dim)
    __shared__ __align__(16) __half wAr[24 * 264];   // r0T rows (256)
    __shared__ __align__(16) __half wB [24 * 264];   // k1T rows
    __shared__ __align__(16) __half wBr[24 * 264];   // r1T rows
    __shared__ __align__(16) __half xa [8 * 408];    // [p|att] per batch (384)
    __shared__ __align__(16) __half xh [16 * 264];   // two 256-inputs per batch
    __shared__ __align__(16) float  gxs[24 * 9], ghs[24 * 9];
    __shared__ __align__(16) float  vl[DD];
    __shared__ __align__(16) __half h1s[DD];
    __shared__ __align__(16) float  qs[DD];
    __shared__ __align__(16) float  sc2[128 * 2];
    __shared__ __align__(16) float  we[128];
    __shared__ __align__(16) float  redd[4];
    __shared__ __align__(16) __half ins[2 * DD + 8];
    __shared__ __align__(16) float  part[4 * 68];

    const int tid = threadIdx.x;
    const int g   = blockIdx.x & 7;    // batch group: b = g + 8m
    const int ht  = blockIdx.x >> 3;   // h-dim tile: d = ht*8 + dd
    const int cb  = blockIdx.x & 63;   // phase C/D batch
    const int ceq = blockIdx.x >> 6;   // phase C e-chunk / phase D col-chunk

    // ---- one-time LDS weight residency ----
    for (int idx = tid; idx < 24 * 384; idx += NTHR) {
        int n = idx / 384, i = idx - n * 384;
        int gc = ((n >> 3) << 8) + (ht << 3) + (n & 7);
        wA[n * 392 + i] = k0T[gc * 384 + i];
    }
    for (int idx = tid; idx < 24 * 256; idx += NTHR) {
        int n = idx >> 8, i = idx & 255;
        int gc = ((n >> 3) << 8) + (ht << 3) + (n & 7);
        wAr[n * 264 + i] = r0T[gc * 256 + i];
        wB [n * 264 + i] = k1T[gc * 256 + i];
        wBr[n * 264 + i] = r1T[gc * 256 + i];
    }
    if (tid < DD) vl[tid] = v[tid];
    int mm = 0, nn = 0;
    float bAi = 0.f, bArr = 0.f, bBi = 0.f, bBrr = 0.f;
    if (tid < 192) {
        mm = tid & 7; nn = tid >> 3;
        int gc = ((nn >> 3) << 8) + (ht << 3) + (nn & 7);
        bAi = bi0[gc]; bArr = br0[gc]; bBi = bi1[gc]; bBrr = br1[gc];
    }
    __syncthreads();

    #pragma unroll 1
    for (int t = 0; t < TDEC; t++) {
        // ================= Phase A: GRU0 =================
        for (int idx = tid; idx < 8 * 192; idx += NTHR) {
            int m = idx / 192, k = idx - m * 192;
            int b = g + (m << 3);
            __half2 val;
            if (k < 64) val = ((const __half2*)(p_h + ((size_t)b * TDEC + t) * PRE))[k];
            else        val = ((const __half2*)(att_h + b * DD))[k - 64];
            ((__half2*)(xa + m * 408))[k] = val;
        }
        for (int idx = tid; idx < 8 * 128; idx += NTHR) {
            int m = idx >> 7, k = idx & 127;
            ((__half2*)(xh + m * 264))[k] = ((const __half2*)(h0_h + (g + (m << 3)) * DD))[k];
        }
        __syncthreads();
        if (tid < 192) {
            const float4* wr  = (const float4*)(wA + nn * 392);
            const float4* xr  = (const float4*)(xa + mm * 408);
            float acc = bAi;
            #pragma unroll 8
            for (int i = 0; i < 48; i++) acc = dot8f(wr[i], xr[i], acc);
            const float4* wr2 = (const float4*)(wAr + nn * 264);
            const float4* xr2 = (const float4*)(xh + mm * 264);
            float acc2 = bArr;
            #pragma unroll 8
            for (int i = 0; i < 32; i++) acc2 = dot8f(wr2[i], xr2[i], acc2);
            gxs[nn * 9 + mm] = acc; ghs[nn * 9 + mm] = acc2;
        }
        __syncthreads();
        if (tid < 64) {
            int m = tid & 7, dd = tid >> 3;
            float xz  = gxs[dd * 9 + m],        hz  = ghs[dd * 9 + m];
            float xr_ = gxs[(8 + dd) * 9 + m],  hr  = ghs[(8 + dd) * 9 + m];
            float xc  = gxs[(16 + dd) * 9 + m], hcv = ghs[(16 + dd) * 9 + m];
            float z = fsig(xz + hz);
            float r = fsig(xr_ + hr);
            float cand = ftanh(xc + r * hcv);
            int b = g + (m << 3), d = (ht << 3) + dd;
            float hold = h0_f[b * DD + d];
            float hn = z * hold + (1.0f - z) * cand;
            h0_f[b * DD + d] = hn;
            h0_h[b * DD + d] = __float2half(hn);
        }
        gbar(bar_cnt, bar_gen);

        // ================= Phase B: GRU1 =================
        for (int idx = tid; idx < 8 * 128; idx += NTHR) {
            int m = idx >> 7, k = idx & 127;
            int b = g + (m << 3);
            ((__half2*)(xh + m * 264))[k]       = ((const __half2*)(h0_h + b * DD))[k];
            ((__half2*)(xh + (8 + m) * 264))[k] = ((const __half2*)(h1_h + b * DD))[k];
        }
        __syncthreads();
        if (tid < 192) {
            const float4* wr  = (const float4*)(wB + nn * 264);
            const float4* xr  = (const float4*)(xh + mm * 264);
            float acc = bBi;
            #pragma unroll 8
            for (int i = 0; i < 32; i++) acc = dot8f(wr[i], xr[i], acc);
            const float4* wr2 = (const float4*)(wBr + nn * 264);
            const float4* xr2 = (const float4*)(xh + (8 + mm) * 264);
            float acc2 = bBrr;
            #pragma unroll 8
            for (int i = 0; i < 32; i++) acc2 = dot8f(wr2[i], xr2[i], acc2);
            gxs[nn * 9 + mm] = acc; ghs[nn * 9 + mm] = acc2;
        }
        __syncthreads();
        if (tid < 64) {
            int m = tid & 7, dd = tid >> 3;
            float xz  = gxs[dd * 9 + m],        hz  = ghs[dd * 9 + m];
            float xr_ = gxs[(8 + dd) * 9 + m],  hr  = ghs[(8 + dd) * 9 + m];
            float xc  = gxs[(16 + dd) * 9 + m], hcv = ghs[(16 + dd) * 9 + m];
            float z = fsig(xz + hz);
            float r = fsig(xr_ + hr);
            float cand = ftanh(xc + r * hcv);
            int b = g + (m << 3), d = (ht << 3) + dd;
            float hold = h1_f[b * DD + d];
            float hn = z * hold + (1.0f - z) * cand;
            h1_f[b * DD + d] = hn;
            h1_h[b * DD + d] = __float2half(hn);
        }
        gbar(bar_cnt, bar_gen);

        // ================= Phase C: q, scores, partial softmax =================
        if (tid < 128) ((__half2*)h1s)[tid] = ((const __half2*)(h1_h + cb * DD))[tid];
        __syncthreads();
        {   // q[d] = sum_i h1[i] * Wq[i][d]
            int d = tid;
            float acc = 0.0f;
            #pragma unroll 4
            for (int i = 0; i < DD; i++)
                acc = fmaf(__half2float(h1s[i]), __half2float(Wq_h[i * DD + d]), acc);
            qs[d] = acc;
        }
        __syncthreads();
        {   // score halves: thread -> (e, half)
            int e = tid >> 1, hf = tid & 1;
            const float4* kp = (const float4*)(keys_h +
                ((size_t)(cb * TENC + ceq * 128 + e)) * DD + hf * 128);
            const float* qp = qs + hf * 128;
            const float* vp = vl + hf * 128;
            float acc = 0.0f;
            #pragma unroll 4
            for (int i = 0; i < 16; i++) {
                union { float4 f; __half2 h[4]; } u; u.f = kp[i];
                #pragma unroll
                for (int k2 = 0; k2 < 4; k2++) {
                    float2 kv = __half22float2(u.h[k2]);
                    int d2 = i * 8 + k2 * 2;
                    acc = fmaf(ftanh(kv.x + qp[d2]),     vp[d2],     acc);
                    acc = fmaf(ftanh(kv.y + qp[d2 + 1]), vp[d2 + 1], acc);
                }
            }
            sc2[e * 2 + hf] = acc;
        }
        __syncthreads();
        {
            float wv = 0.0f;
            if (tid < 128) { wv = __expf(sc2[tid * 2] + sc2[tid * 2 + 1]); we[tid] = wv; }
            float dsum = wv;
            #pragma unroll
            for (int off = 32; off; off >>= 1) dsum += __shfl_down(dsum, off);
            if ((tid & 63) == 0) redd[tid >> 6] = dsum;
        }
        __syncthreads();
        if (tid == 0) den_part[ceq * 64 + cb] = redd[0] + redd[1];
        {   // partial num[d] = sum_e w_e * mem[b][e][d]
            int d = tid;
            const __half* mp = mem_h + ((size_t)(cb * TENC + ceq * 128)) * DD + d;
            float acc = 0.0f;
            #pragma unroll 4
            for (int e2 = 0; e2 < 128; e2++)
                acc = fmaf(__half2float(mp[e2 * DD]), we[e2], acc);
            num_part[(ceq * 64 + cb) * DD + d] = acc;
        }
        gbar(bar_cnt, bar_gen);

        // ================= Phase D: ctx + attn = [h1|ctx]@Wa =================
        {
            int d = tid;
            float den = den_part[cb] + den_part[64 + cb] + den_part[128 + cb] + den_part[192 + cb];
            float nm  = num_part[cb * DD + d]
                      + num_part[(64 + cb) * DD + d]
                      + num_part[(128 + cb) * DD + d]
                      + num_part[(192 + cb) * DD + d];
            float ctxd = nm * __builtin_amdgcn_rcpf(den);
            ins[d]      = h1s[d];                 // h1 (fp16, staged in phase C)
            ins[DD + d] = __float2half(ctxd);
        }
        __syncthreads();
        {
            int c = tid & 63, rq = tid >> 6;
            const __half* wp = Wa_h + (size_t)(rq * 128) * DD + (ceq << 6) + c;
            const __half* ip = ins + rq * 128;
            float acc = 0.0f;
            #pragma unroll 4
            for (int i = 0; i < 128; i++)
                acc = fmaf(__half2float(ip[i]), __half2float(wp[i * DD]), acc);
            part[rq * 68 + c] = acc;
        }
        __syncthreads();
        if (tid < 64) {
            float a = part[tid] + part[68 + tid] + part[136 + tid] + part[204 + tid];
            int oc = (ceq << 6) + tid;
            att_h[cb * DD + oc] = __float2half(a);
            ahist_h[((size_t)cb * TDEC + t) * DD + oc] = __float2half(a);
        }
        gbar(bar_cnt, bar_gen);
    }
}

extern "C" void kernel_launch(void* const* d_in, const int* in_sizes, int n_in,
                              void* d_out, int out_size, void* d_ws, size_t ws_size,
                              hipStream_t stream)
{
    const float* dec    = (const float*)d_in[0];
    const float* memory = (const float*)d_in[1];
    const float* W1  = (const float*)d_in[2];
    const float* b1  = (const float*)d_in[3];
    const float* W2  = (const float*)d_in[4];
    const float* b2  = (const float*)d_in[5];
    const float* k0  = (const float*)d_in[6];
    const float* r0  = (const float*)d_in[7];
    const float* bi0 = (const float*)d_in[8];
    const float* br0 = (const float*)d_in[9];
    const float* k1  = (const float*)d_in[10];
    const float* r1  = (const float*)d_in[11];
    const float* bi1 = (const float*)d_in[12];
    const float* br1 = (const float*)d_in[13];
    const float* Wq  = (const float*)d_in[14];
    const float* Wm  = (const float*)d_in[15];
    const float* v   = (const float*)d_in[16];
    const float* Wa  = (const float*)d_in[17];
    const float* Wo  = (const float*)d_in[18];
    const float* bo  = (const float*)d_in[19];
    float* out = (float*)d_out;

    // ---- workspace layout (256B-aligned chunks) ----
    char* w = (char*)d_ws;
    size_t off = 0;
    int*    bar    = (int*)(w + off);          off += 256;
    __half* att_h  = (__half*)(w + off);       off += (size_t)BB * DD * 2;        // 32768
    float*  h0_f   = (float*)(w + off);        off += (size_t)BB * DD * 4;        // 65536
    __half* h0_h   = (__half*)(w + off);       off += (size_t)BB * DD * 2;
    float*  h1_f   = (float*)(w + off);        off += (size_t)BB * DD * 4;
    __half* h1_h   = (__half*)(w + off);       off += (size_t)BB * DD * 2;
    size_t zero_bytes = off;                   // bar + state, zeroed every call
    __half* p_h    = (__half*)(w + off);       off += (size_t)BB * TDEC * PRE * 2;
    __half* keys_h = (__half*)(w + off);       off += (size_t)BB * TENC * DD * 2;
    __half* mem_h  = (__half*)(w + off);       off += (size_t)BB * TENC * DD * 2;
    __half* k0T    = (__half*)(w + off);       off += (size_t)G3 * 384 * 2;
    __half* r0T    = (__half*)(w + off);       off += (size_t)G3 * DD * 2;
    __half* k1T    = (__half*)(w + off);       off += (size_t)G3 * DD * 2;
    __half* r1T    = (__half*)(w + off);       off += (size_t)G3 * DD * 2;
    __half* Wq_h   = (__half*)(w + off);       off += (size_t)DD * DD * 2;
    __half* Wa_h   = (__half*)(w + off);       off += (size_t)2 * DD * DD * 2;
    float*  num_part = (float*)(w + off);      off += (size_t)4 * BB * DD * 4;
    float*  den_part = (float*)(w + off);      off += 1024;
    __half* ahist_h  = (__half*)(w + off);     off += (size_t)BB * TDEC * DD * 2;

    // zero barrier + recurrent state
    hipMemsetAsync(w, 0, zero_bytes, stream);

    // precompute (parallel, outside the recurrence)
    prenet_kernel<<<BB * TDEC / 8, 256, 0, stream>>>(dec, W1, b1, W2, b2, p_h);
    keys_kernel<<<BB * TENC / 8, 256, 0, stream>>>(memory, Wm, keys_h);
    cvt_half_kernel<<<(BB * TENC * DD / 2 + 255) / 256, 256, 0, stream>>>(
        memory, mem_h, BB * TENC * DD / 2);
    cvt_half_kernel<<<(DD * DD / 2 + 255) / 256, 256, 0, stream>>>(Wq, Wq_h, DD * DD / 2);
    cvt_half_kernel<<<(2 * DD * DD / 2 + 255) / 256, 256, 0, stream>>>(Wa, Wa_h, DD * DD);
    transpose_cvt_kernel<<<(G3 * 384 + 255) / 256, 256, 0, stream>>>(k0, k0T, 384, G3);
    transpose_cvt_kernel<<<(G3 * DD + 255) / 256, 256, 0, stream>>>(r0, r0T, DD, G3);
    transpose_cvt_kernel<<<(G3 * DD + 255) / 256, 256, 0, stream>>>(k1, k1T, DD, G3);
    transpose_cvt_kernel<<<(G3 * DD + 255) / 256, 256, 0, stream>>>(r1, r1T, DD, G3);

    // the 400-step recurrence on a persistent cooperative grid
    decoder_kernel<<<NBLK, NTHR, 0, stream>>>(
        p_h, keys_h, mem_h, k0T, r0T, k1T, r1T, Wq_h, Wa_h,
        bi0, br0, bi1, br1, v,
        num_part, den_part, att_h, h0_f, h0_h, h1_f, h1_h, ahist_h,
        bar, bar + 1);

    // output projection (outside the recurrence)
    out_kernel<<<BB * TDEC / 8, 448, 0, stream>>>(ahist_h, Wo, bo, out);
}

// Round 3
// 17710.866 us; speedup vs baseline: 3.2115x; 3.2115x over previous
//
#include <hip/hip_runtime.h>
#include <hip/hip_fp16.h>

#define BB   64
#define TDEC 400
#define TENC 512
#define DD   256
#define PRE  128
#define NOUT 400
#define G3   768

typedef _Float16 h2_t __attribute__((ext_vector_type(2)));

// ---------------- fast math ----------------
__device__ __forceinline__ float fsig(float x) {
    return __builtin_amdgcn_rcpf(1.0f + __expf(-x));
}
__device__ __forceinline__ float ftanh(float x) {
    float t = __expf(2.0f * x);
    return 1.0f - 2.0f * __builtin_amdgcn_rcpf(t + 1.0f);
}
// 8-term fp16 x fp16 -> fp32 dot from two 16B packets
__device__ __forceinline__ float dot8(float4 w, float4 x, float acc) {
    union { float4 f; h2_t h[4]; } uw, ux;
    uw.f = w; ux.f = x;
#if __has_builtin(__builtin_amdgcn_fdot2)
    #pragma unroll
    for (int k = 0; k < 4; k++)
        acc = __builtin_amdgcn_fdot2(uw.h[k], ux.h[k], acc, false);
#else
    #pragma unroll
    for (int k = 0; k < 4; k++) {
        acc = fmaf((float)uw.h[k].x, (float)ux.h[k].x, acc);
        acc = fmaf((float)uw.h[k].y, (float)ux.h[k].y, acc);
    }
#endif
    return acc;
}

// ---------------- prenet: p_h = fp16(relu(relu(x@W1+b1)@W2+b2)) ----------------
__global__ __launch_bounds__(256) void prenet_kernel(
    const float* __restrict__ x, const float* __restrict__ W1, const float* __restrict__ b1,
    const float* __restrict__ W2, const float* __restrict__ b2, __half* __restrict__ p_h)
{
    __shared__ __align__(16) float xs[8][NOUT];
    __shared__ __align__(16) float hs[8][DD];
    const int row0 = blockIdx.x * 8;
    const int tid = threadIdx.x;
    for (int idx = tid; idx < 8 * NOUT; idx += 256) {
        int m = idx / NOUT, i = idx - m * NOUT;
        xs[m][i] = x[(size_t)(row0 + m) * NOUT + i];
    }
    __syncthreads();
    {
        const int j = tid;
        float acc[8];
        float bj = b1[j];
        #pragma unroll
        for (int m = 0; m < 8; m++) acc[m] = bj;
        #pragma unroll 4
        for (int i = 0; i < NOUT; i++) {
            float w = W1[i * DD + j];
            #pragma unroll
            for (int m = 0; m < 8; m++) acc[m] = fmaf(xs[m][i], w, acc[m]);
        }
        #pragma unroll
        for (int m = 0; m < 8; m++) hs[m][j] = fmaxf(acc[m], 0.0f);
    }
    __syncthreads();
    if (tid < PRE) {
        const int j = tid;
        float acc[8];
        float bj = b2[j];
        #pragma unroll
        for (int m = 0; m < 8; m++) acc[m] = bj;
        #pragma unroll 4
        for (int i = 0; i < DD; i++) {
            float w = W2[i * PRE + j];
            #pragma unroll
            for (int m = 0; m < 8; m++) acc[m] = fmaf(hs[m][i], w, acc[m]);
        }
        #pragma unroll
        for (int m = 0; m < 8; m++)
            p_h[(size_t)(row0 + m) * PRE + j] = __float2half(fmaxf(acc[m], 0.0f));
    }
}

// ---------------- keys_h[b*TENC+e][d] = fp16(memory @ Wm) ----------------
__global__ __launch_bounds__(256) void keys_kernel(
    const float* __restrict__ mem, const float* __restrict__ Wm, __half* __restrict__ keys_h)
{
    __shared__ __align__(16) float xs[8][DD];
    const int row0 = blockIdx.x * 8;
    const int tid = threadIdx.x;
    for (int idx = tid; idx < 8 * DD; idx += 256) {
        int m = idx >> 8, i = idx & 255;
        xs[m][i] = mem[(size_t)(row0 + m) * DD + i];
    }
    __syncthreads();
    const int j = tid;
    float acc[8] = {0.f,0.f,0.f,0.f,0.f,0.f,0.f,0.f};
    #pragma unroll 4
    for (int i = 0; i < DD; i++) {
        float w = Wm[i * DD + j];
        #pragma unroll
        for (int m = 0; m < 8; m++) acc[m] = fmaf(xs[m][i], w, acc[m]);
    }
    #pragma unroll
    for (int m = 0; m < 8; m++) keys_h[(size_t)(row0 + m) * DD + j] = __float2half(acc[m]);
}

// ---------------- weight pack: src[R][C] fp32 -> dst[(i8*C + j)*8 + k] = fp16 src[8*i8+k][j] ----------------
__global__ __launch_bounds__(256) void pack_w_kernel(
    const float* __restrict__ src, __half* __restrict__ dst, int R, int C)
{
    int flat = blockIdx.x * 256 + threadIdx.x;
    if (flat < R * C) {
        int k = flat & 7;
        int t2 = flat >> 3;
        int j = t2 % C;
        int i8 = t2 / C;
        dst[flat] = __float2half(src[(size_t)(8 * i8 + k) * C + j]);
    }
}

// ---------------- mem pack: dst[b*65536 + e2*256 + d] = {mem[b][2e2][d], mem[b][2e2+1][d]} ----------------
__global__ __launch_bounds__(256) void pack_mem_kernel(
    const float* __restrict__ mem, __half2* __restrict__ dst)
{
    int flat = blockIdx.x * 256 + threadIdx.x;
    if (flat < BB * 256 * 256) {
        int d  = flat & 255;
        int e2 = (flat >> 8) & 255;
        int b  = flat >> 16;
        const float* base = mem + ((size_t)b * TENC + 2 * e2) * DD + d;
        dst[flat] = __floats2half2_rn(base[0], base[DD]);
    }
}

// ---------------- y = ahist(fp16) @ Wo + bo ----------------
__global__ __launch_bounds__(448) void out_kernel(
    const __half* __restrict__ ah, const float* __restrict__ Wo, const float* __restrict__ bo,
    float* __restrict__ y)
{
    __shared__ __align__(16) float xs[8][DD];
    const int row0 = blockIdx.x * 8;
    const int tid = threadIdx.x;
    for (int idx = tid; idx < 8 * DD; idx += 448) {
        int m = idx >> 8, i = idx & 255;
        xs[m][i] = __half2float(ah[(size_t)(row0 + m) * DD + i]);
    }
    __syncthreads();
    if (tid < NOUT) {
        const int j = tid;
        float acc[8];
        float bj = bo[j];
        #pragma unroll
        for (int m = 0; m < 8; m++) acc[m] = bj;
        #pragma unroll 4
        for (int i = 0; i < DD; i++) {
            float w = Wo[i * NOUT + j];
            #pragma unroll
            for (int m = 0; m < 8; m++) acc[m] = fmaf(xs[m][i], w, acc[m]);
        }
        #pragma unroll
        for (int m = 0; m < 8; m++) y[(size_t)(row0 + m) * NOUT + j] = acc[m];
    }
}

// ---------------- decoder: 64 blocks (1/batch elem) x 768 threads, no grid sync ----------------
// fp16 operands, fp32 state/accum. Weights stream from per-XCD L2 (2.2 MB fp16 set,
// identical reads across the 8 blocks of an XCD -> L2-resident).
__global__ __launch_bounds__(768) void decoder_kernel(
    const __half* __restrict__ p_h,  const __half* __restrict__ keys_h,
    const __half2* __restrict__ mem_p,
    const __half* __restrict__ k0p,  const __half* __restrict__ r0p,
    const __half* __restrict__ k1p,  const __half* __restrict__ r1p,
    const __half* __restrict__ Wqp,  const __half* __restrict__ Wap,
    const float* __restrict__ bi0, const float* __restrict__ br0,
    const float* __restrict__ bi1, const float* __restrict__ br1,
    const float* __restrict__ v,   __half* __restrict__ ahist)
{
    __shared__ __align__(16) __half xa[384];            // [p_t(128) | att(256)] fp16
    __shared__ __align__(16) __half h0s[DD], h1s[DD];   // state fp16 (dot operands)
    __shared__ __align__(16) __half ctxh[DD], vh[DD];
    __shared__ __align__(16) __half qvh[2 * DD];        // interleaved {q[d], v[d]} fp16
    __shared__ __align__(16) float h0f[DD], h1f[DD];    // state fp32 (exact carry)
    __shared__ __align__(16) float gx[G3], gh[G3];
    __shared__ __align__(16) float sc[TENC];            // exp(score)
    __shared__ __align__(16) float hWa[DD];             // h1 @ Wa_top
    __shared__ __align__(16) float b0i[G3], b0r[G3], b1i[G3], b1r[G3];
    __shared__ float redd[16];

    const int tid = threadIdx.x;
    const int b = blockIdx.x;

    b0i[tid] = bi0[tid]; b0r[tid] = br0[tid]; b1i[tid] = bi1[tid]; b1r[tid] = br1[tid];
    if (tid < DD) {
        h0f[tid] = 0.0f; h1f[tid] = 0.0f;
        h0s[tid] = __float2half(0.0f); h1s[tid] = __float2half(0.0f);
        vh[tid] = __float2half(v[tid]);
        xa[PRE + tid] = __float2half(0.0f);   // att_0 = 0
    }
    __syncthreads();

    const __half*  keyb = keys_h + (size_t)b * TENC * DD;
    const __half2* memb = mem_p + (size_t)b * (TENC / 2) * DD;
    const __half*  pb   = p_h + (size_t)b * TDEC * PRE;

    #pragma unroll 1
    for (int t = 0; t < TDEC; t++) {
        // ---- stage prenet input ----
        if (tid < 64) ((__half2*)xa)[tid] = ((const __half2*)(pb + t * PRE))[tid];
        __syncthreads();

        // ---- GRU0 gates: gx = [p|att]@k0 + bi0 ; gh = h0@r0 + br0 ----
        {
            const int j = tid;
            const float4* wp = (const float4*)k0p;
            const float4* xp = (const float4*)xa;
            float acc = b0i[j];
            #pragma unroll 8
            for (int i8 = 0; i8 < 48; i8++) acc = dot8(wp[i8 * G3 + j], xp[i8], acc);
            const float4* wp2 = (const float4*)r0p;
            const float4* hp  = (const float4*)h0s;
            float acc2 = b0r[j];
            #pragma unroll 8
            for (int i8 = 0; i8 < 32; i8++) acc2 = dot8(wp2[i8 * G3 + j], hp[i8], acc2);
            gx[j] = acc; gh[j] = acc2;
        }
        __syncthreads();
        if (tid < DD) {
            float z = fsig(gx[tid] + gh[tid]);
            float r = fsig(gx[DD + tid] + gh[DD + tid]);
            float cand = ftanh(gx[2 * DD + tid] + r * gh[2 * DD + tid]);
            float hn = z * h0f[tid] + (1.0f - z) * cand;
            h0f[tid] = hn; h0s[tid] = __float2half(hn);
        }
        __syncthreads();

        // ---- GRU1 gates: gx = h0n@k1 + bi1 ; gh = h1@r1 + br1 ----
        {
            const int j = tid;
            const float4* wp = (const float4*)k1p;
            const float4* xp = (const float4*)h0s;
            float acc = b1i[j];
            #pragma unroll 8
            for (int i8 = 0; i8 < 32; i8++) acc = dot8(wp[i8 * G3 + j], xp[i8], acc);
            const float4* wp2 = (const float4*)r1p;
            const float4* hp  = (const float4*)h1s;
            float acc2 = b1r[j];
            #pragma unroll 8
            for (int i8 = 0; i8 < 32; i8++) acc2 = dot8(wp2[i8 * G3 + j], hp[i8], acc2);
            gx[j] = acc; gh[j] = acc2;
        }
        __syncthreads();
        if (tid < DD) {
            float z = fsig(gx[tid] + gh[tid]);
            float r = fsig(gx[DD + tid] + gh[DD + tid]);
            float cand = ftanh(gx[2 * DD + tid] + r * gh[2 * DD + tid]);
            float hn = z * h1f[tid] + (1.0f - z) * cand;
            h1f[tid] = hn; h1s[tid] = __float2half(hn);
        }
        __syncthreads();

        // ---- q = h1n @ Wq (fp16, interleaved with v for the score loop) ----
        if (tid < DD) {
            const float4* wp = (const float4*)Wqp;
            const float4* hp = (const float4*)h1s;
            float acc = 0.0f;
            #pragma unroll 8
            for (int i8 = 0; i8 < 32; i8++) acc = dot8(wp[i8 * DD + tid], hp[i8], acc);
            qvh[2 * tid]     = __float2half(acc);
            qvh[2 * tid + 1] = vh[tid];
        }
        __syncthreads();

        // ---- scores (512 thr) + h1@Wa_top (256 thr), concurrent ----
        if (tid < TENC) {
            const float4* kp = (const float4*)(keyb + (size_t)tid * DD);
            const float4* qp = (const float4*)qvh;
            float s = 0.0f;
            #pragma unroll 4
            for (int i8 = 0; i8 < 32; i8++) {
                union { float4 f; h2_t h[4]; } uk, u0, u1;
                uk.f = kp[i8]; u0.f = qp[2 * i8]; u1.f = qp[2 * i8 + 1];
                s = fmaf((float)u0.h[0].y, ftanh((float)uk.h[0].x + (float)u0.h[0].x), s);
                s = fmaf((float)u0.h[1].y, ftanh((float)uk.h[0].y + (float)u0.h[1].x), s);
                s = fmaf((float)u0.h[2].y, ftanh((float)uk.h[1].x + (float)u0.h[2].x), s);
                s = fmaf((float)u0.h[3].y, ftanh((float)uk.h[1].y + (float)u0.h[3].x), s);
                s = fmaf((float)u1.h[0].y, ftanh((float)uk.h[2].x + (float)u1.h[0].x), s);
                s = fmaf((float)u1.h[1].y, ftanh((float)uk.h[2].y + (float)u1.h[1].x), s);
                s = fmaf((float)u1.h[2].y, ftanh((float)uk.h[3].x + (float)u1.h[2].x), s);
                s = fmaf((float)u1.h[3].y, ftanh((float)uk.h[3].y + (float)u1.h[3].x), s);
            }
            float wv = __expf(s);   // |s| <= ~11, no max-shift needed in fp32
            sc[tid] = wv;
            #pragma unroll
            for (int off = 32; off; off >>= 1) wv += __shfl_down(wv, off);
            if ((tid & 63) == 0) redd[tid >> 6] = wv;
        } else {
            const int d = tid - TENC;
            const float4* wp = (const float4*)Wap;
            const float4* hp = (const float4*)h1s;
            float acc = 0.0f;
            #pragma unroll 8
            for (int i8 = 0; i8 < 32; i8++) acc = dot8(wp[i8 * DD + d], hp[i8], acc);
            hWa[d] = acc;
        }
        __syncthreads();
        if (tid == 0) {
            float ssum = 0.0f;
            #pragma unroll
            for (int i = 0; i < 8; i++) ssum += redd[i];
            redd[8] = ssum;
        }
        __syncthreads();

        // ---- ctx[d] = sum_e sc[e] * mem[e][d] / S ----
        if (tid < DD) {
            const float invS = __builtin_amdgcn_rcpf(redd[8]);
            const float4* scp = (const float4*)sc;
            float acc = 0.0f;
            #pragma unroll 4
            for (int e8 = 0; e8 < 64; e8++) {
                float4 w0 = scp[2 * e8], w1 = scp[2 * e8 + 1];
                __half2 m0 = memb[(4 * e8 + 0) * DD + tid];
                __half2 m1 = memb[(4 * e8 + 1) * DD + tid];
                __half2 m2 = memb[(4 * e8 + 2) * DD + tid];
                __half2 m3 = memb[(4 * e8 + 3) * DD + tid];
                float2 f0 = __half22float2(m0), f1 = __half22float2(m1);
                float2 f2 = __half22float2(m2), f3 = __half22float2(m3);
                acc = fmaf(f0.x, w0.x, acc); acc = fmaf(f0.y, w0.y, acc);
                acc = fmaf(f1.x, w0.z, acc); acc = fmaf(f1.y, w0.w, acc);
                acc = fmaf(f2.x, w1.x, acc); acc = fmaf(f2.y, w1.y, acc);
                acc = fmaf(f3.x, w1.z, acc); acc = fmaf(f3.y, w1.w, acc);
            }
            ctxh[tid] = __float2half(acc * invS);
        }
        __syncthreads();

        // ---- attn = hWa + ctx @ Wa_bot ; carry (fp16) + log ----
        if (tid < DD) {
            const float4* wp = (const float4*)Wap;
            const float4* cp = (const float4*)ctxh;
            float acc = hWa[tid];
            #pragma unroll 8
            for (int i8 = 0; i8 < 32; i8++) acc = dot8(wp[(32 + i8) * DD + tid], cp[i8], acc);
            __half ah = __float2half(acc);
            xa[PRE + tid] = ah;
            ahist[((size_t)b * TDEC + t) * DD + tid] = ah;
        }
        __syncthreads();
    }
}

extern "C" void kernel_launch(void* const* d_in, const int* in_sizes, int n_in,
                              void* d_out, int out_size, void* d_ws, size_t ws_size,
                              hipStream_t stream)
{
    const float* dec    = (const float*)d_in[0];
    const float* memory = (const float*)d_in[1];
    const float* W1  = (const float*)d_in[2];
    const float* b1  = (const float*)d_in[3];
    const float* W2  = (const float*)d_in[4];
    const float* b2  = (const float*)d_in[5];
    const float* k0  = (const float*)d_in[6];
    const float* r0  = (const float*)d_in[7];
    const float* bi0 = (const float*)d_in[8];
    const float* br0 = (const float*)d_in[9];
    const float* k1  = (const float*)d_in[10];
    const float* r1  = (const float*)d_in[11];
    const float* bi1 = (const float*)d_in[12];
    const float* br1 = (const float*)d_in[13];
    const float* Wq  = (const float*)d_in[14];
    const float* Wm  = (const float*)d_in[15];
    const float* v   = (const float*)d_in[16];
    const float* Wa  = (const float*)d_in[17];
    const float* Wo  = (const float*)d_in[18];
    const float* bo  = (const float*)d_in[19];
    float* out = (float*)d_out;
    (void)ws_size; (void)in_sizes; (void)n_in; (void)out_size;

    // ---- workspace layout (fp16 packs) ----
    char* w = (char*)d_ws;
    size_t off = 0;
    __half*  p_h    = (__half*)(w + off);  off += (size_t)BB * TDEC * PRE * 2;   // 6.55 MB
    __half*  keys_h = (__half*)(w + off);  off += (size_t)BB * TENC * DD * 2;    // 16.8 MB
    __half2* mem_p  = (__half2*)(w + off); off += (size_t)BB * TENC * DD * 2;    // 16.8 MB
    __half*  k0p    = (__half*)(w + off);  off += (size_t)384 * G3 * 2;
    __half*  r0p    = (__half*)(w + off);  off += (size_t)DD * G3 * 2;
    __half*  k1p    = (__half*)(w + off);  off += (size_t)DD * G3 * 2;
    __half*  r1p    = (__half*)(w + off);  off += (size_t)DD * G3 * 2;
    __half*  Wqp    = (__half*)(w + off);  off += (size_t)DD * DD * 2;
    __half*  Wap    = (__half*)(w + off);  off += (size_t)2 * DD * DD * 2;
    __half*  ahist  = (__half*)(w + off);  off += (size_t)BB * TDEC * DD * 2;    // 13.1 MB

    // precompute (all parallel, outside the recurrence)
    prenet_kernel<<<BB * TDEC / 8, 256, 0, stream>>>(dec, W1, b1, W2, b2, p_h);
    keys_kernel<<<BB * TENC / 8, 256, 0, stream>>>(memory, Wm, keys_h);
    pack_mem_kernel<<<(BB * 256 * 256) / 256, 256, 0, stream>>>(memory, mem_p);
    pack_w_kernel<<<(384 * G3 + 255) / 256, 256, 0, stream>>>(k0, k0p, 384, G3);
    pack_w_kernel<<<(DD * G3 + 255) / 256, 256, 0, stream>>>(r0, r0p, DD, G3);
    pack_w_kernel<<<(DD * G3 + 255) / 256, 256, 0, stream>>>(k1, k1p, DD, G3);
    pack_w_kernel<<<(DD * G3 + 255) / 256, 256, 0, stream>>>(r1, r1p, DD, G3);
    pack_w_kernel<<<(DD * DD + 255) / 256, 256, 0, stream>>>(Wq, Wqp, DD, DD);
    pack_w_kernel<<<(2 * DD * DD + 255) / 256, 256, 0, stream>>>(Wa, Wap, 2 * DD, DD);

    // the 400-step recurrence: one block per batch element, no device-scope sync
    decoder_kernel<<<BB, 768, 0, stream>>>(p_h, keys_h, mem_p, k0p, r0p, k1p, r1p,
                                           Wqp, Wap, bi0, br0, bi1, br1, v, ahist);

    // output projection (outside the recurrence)
    out_kernel<<<BB * TDEC / 8, 448, 0, stream>>>(ahist, Wo, bo, out);
}